// Round 15
// baseline (98.807 us; speedup 1.0000x reference)
//
#include <hip/hip_runtime.h>
#include <stdint.h>

typedef __attribute__((ext_vector_type(8))) _Float16 f16x8;
typedef __attribute__((ext_vector_type(4))) float f32x4;

#define MARG 0.09375f

// async global->LDS, 16B per lane (used by fallback path)
__device__ __forceinline__ void glds16(const void* g, void* l) {
  __builtin_amdgcn_global_load_lds(
      (const __attribute__((address_space(1))) void*)g,
      (__attribute__((address_space(3))) void*)l, 16, 0, 0);
}

__device__ __forceinline__ unsigned short f2h(float f) {
  return __builtin_bit_cast(unsigned short, (_Float16)f);  // RN
}

// ---------------- prep cb: fp16 convert + hc[k] = 0.5*|c_k|^2; zero counter -------
__global__ __launch_bounds__(256) void vq_prep_cb(const float* __restrict__ cb,
                                                  unsigned short* __restrict__ cbh,
                                                  float* __restrict__ hc,
                                                  int* __restrict__ count) {
  int w = threadIdx.x >> 6, lane = threadIdx.x & 63;
  int row = blockIdx.x * 4 + w;
  size_t off = (size_t)row * 256 + lane * 4;
  float4 v = *reinterpret_cast<const float4*>(cb + off);
  ushort4 h;
  h.x = f2h(v.x); h.y = f2h(v.y); h.z = f2h(v.z); h.w = f2h(v.w);
  *reinterpret_cast<ushort4*>(cbh + off) = h;
  float s = v.x * v.x + v.y * v.y + v.z * v.z + v.w * v.w;
#pragma unroll
  for (int m = 32; m >= 1; m >>= 1) s += __shfl_xor(s, m, 64);
  if (lane == 0) hc[row] = 0.5f * s;
  if (blockIdx.x == 0 && threadIdx.x == 0) *count = 0;
}

// ---- main v3: barrier-free reg-streaming fp16 MFMA ----
// 512 thr = 8 waves. Block = 64 rows x all 1024 codes. ALL waves share the 64 rows
// (A in fragment-ordered LDS, read-only after one sync); wave w owns codes
// [w*128,(w+1)*128), processed as 4 passes of 32 codes x full K=256.
// B fragments load DIRECTLY from L2 to registers (16 codes x 64B coalesced lines)
// -> zero barriers in the main loop; block B traffic = 512KB (same as staged).
// A_lds layout is frag-major: frag(rt,kst) at (rt*8+kst)*1024 + lane*16 bytes.
__global__ __launch_bounds__(512, 2) void vq_mfma_kernel(
    const float* __restrict__ x, const unsigned short* __restrict__ cbh,
    const float* __restrict__ hc, int* __restrict__ out,
    int* __restrict__ list, int* __restrict__ count) {
  __shared__ unsigned short Alds[16384];  // 32 KB, frag-major
  __shared__ float c2s[1024];             // 4 KB
  __shared__ float cbv[8][64];            // cross-wave merge: best
  __shared__ int   cbi[8][64];            //   index
  __shared__ float csv[8][64];            //   second-best

  const int tid = threadIdx.x;
  const int lane = tid & 63;
  const int wave = tid >> 6;
  const int l15 = lane & 15;
  const int l4  = lane >> 4;  // 0..3
  // XCD-aware swizzle: 512 blocks, 8 XCDs -> contiguous 64-block chunks per XCD
  const int bswz = (blockIdx.x & 7) * 64 + (blockIdx.x >> 3);
  const int r0 = bswz * 64;

  reinterpret_cast<float2*>(c2s)[tid] = reinterpret_cast<const float2*>(hc)[tid];

  // ---- Phase 0: A rows fp32 -> fp16 -> frag-major A_lds (once per block) ----
  {
    const int row = tid >> 3;          // 0..63
    const int cc  = tid & 7;           // dim chunk of 32 (== kst)
    const float* src = x + (size_t)(r0 + row) * 256 + cc * 32;
    unsigned short hv[32];
#pragma unroll
    for (int q = 0; q < 8; ++q) {
      float4 v = *reinterpret_cast<const float4*>(src + q * 4);
      hv[q * 4 + 0] = f2h(v.x); hv[q * 4 + 1] = f2h(v.y);
      hv[q * 4 + 2] = f2h(v.z); hv[q * 4 + 3] = f2h(v.w);
    }
    char* base = reinterpret_cast<char*>(Alds);
    const int rt = row >> 4, rl = row & 15;
#pragma unroll
    for (int j8 = 0; j8 < 4; ++j8) {  // dim octet within the 32-chunk (== l4)
      int byte = (rt * 8 + cc) * 1024 + j8 * 256 + rl * 16;
      *reinterpret_cast<f16x8*>(base + byte) = *reinterpret_cast<const f16x8*>(&hv[j8 * 8]);
    }
  }
  __syncthreads();   // A_lds complete; read-only from here -> no more barriers

  const char* Ab = reinterpret_cast<const char*>(Alds);
  const int laneb = lane * 16;        // A read: vaddr=lane*16, rest imm offsets

  const int cw0 = wave * 128;         // wave's code slice
  const unsigned short* cbw = cbh + (size_t)(cw0 + l15) * 256 + l4 * 8;

  float bestv[4][4], secv[4][4];
  int besti[4][4];
#pragma unroll
  for (int rt = 0; rt < 4; ++rt)
#pragma unroll
    for (int g = 0; g < 4; ++g) {
      bestv[rt][g] = -3.4e38f; secv[rt][g] = -3.4e38f; besti[rt][g] = 0;
    }

  for (int pass = 0; pass < 4; ++pass) {
    f32x4 acc[4][2];
#pragma unroll
    for (int rt = 0; rt < 4; ++rt)
#pragma unroll
      for (int ct = 0; ct < 2; ++ct) acc[rt][ct] = (f32x4){0.f, 0.f, 0.f, 0.f};

    const unsigned short* cbp = cbw + pass * 32 * 256;
#pragma unroll
    for (int kh = 0; kh < 2; ++kh) {
      // B fragments: 2 code-tiles x 4 k-steps, straight from L2
      f16x8 bfr[2][4];
#pragma unroll
      for (int ct = 0; ct < 2; ++ct)
#pragma unroll
        for (int ks = 0; ks < 4; ++ks)
          bfr[ct][ks] = *reinterpret_cast<const f16x8*>(
              cbp + ct * 16 * 256 + kh * 128 + ks * 32);
      // A fragments from LDS (imm-offset ds_read_b128, conflict-free)
      f16x8 afr[4][4];
#pragma unroll
      for (int rt = 0; rt < 4; ++rt)
#pragma unroll
        for (int ks = 0; ks < 4; ++ks)
          afr[rt][ks] = *reinterpret_cast<const f16x8*>(
              Ab + (rt * 8 + kh * 4 + ks) * 1024 + laneb);
#pragma unroll
      for (int ks = 0; ks < 4; ++ks)
#pragma unroll
        for (int rt = 0; rt < 4; ++rt)
#pragma unroll
          for (int ct = 0; ct < 2; ++ct)
            acc[rt][ct] = __builtin_amdgcn_mfma_f32_16x16x32_f16(
                afr[rt][ks], bfr[ct][ks], acc[rt][ct], 0, 0, 0);
    }

    // fold this pass's 32 codes into running best/second (codes ascending)
#pragma unroll
    for (int ct = 0; ct < 2; ++ct) {
      const int code = cw0 + pass * 32 + ct * 16 + l15;
      const float hcv = c2s[code];
#pragma unroll
      for (int rt = 0; rt < 4; ++rt)
#pragma unroll
        for (int g = 0; g < 4; ++g) {
          float sc = acc[rt][ct][g] - hcv;
          bool gt = sc > bestv[rt][g];
          float ns = gt ? bestv[rt][g] : fmaxf(secv[rt][g], sc);
          bestv[rt][g] = gt ? sc : bestv[rt][g];
          besti[rt][g] = gt ? code : besti[rt][g];
          secv[rt][g] = ns;
        }
    }
  }

  // within-wave merge across the 16 l15-lanes (each holds different codes)
#pragma unroll
  for (int rt = 0; rt < 4; ++rt)
#pragma unroll
    for (int g = 0; g < 4; ++g) {
      float bv = bestv[rt][g]; int bi = besti[rt][g]; float sv = secv[rt][g];
#pragma unroll
      for (int m = 1; m < 16; m <<= 1) {
        float ov = __shfl_xor(bv, m, 64);
        int   oi = __shfl_xor(bi, m, 64);
        float os = __shfl_xor(sv, m, 64);
        sv = fmaxf(fmaxf(sv, os), fminf(bv, ov));
        bool gt = (ov > bv) || (ov == bv && oi < bi);
        bv = gt ? ov : bv;
        bi = gt ? oi : bi;
      }
      if (l15 == 0) {
        int rl = rt * 16 + l4 * 4 + g;
        cbv[wave][rl] = bv; cbi[wave][rl] = bi; csv[wave][rl] = sv;
      }
    }

  // cross-wave merge: 8 waves surveyed disjoint 128-code slices
  __syncthreads();
  if (tid < 64) {
    float bv = cbv[0][tid]; int bi = cbi[0][tid]; float sv = csv[0][tid];
#pragma unroll
    for (int w2 = 1; w2 < 8; ++w2) {
      float ov = cbv[w2][tid]; int oi = cbi[w2][tid]; float os = csv[w2][tid];
      sv = fmaxf(fmaxf(sv, os), fminf(bv, ov));
      bool gt = (ov > bv) || (ov == bv && oi < bi);
      bv = gt ? ov : bv;
      bi = gt ? oi : bi;
    }
    out[r0 + tid] = bi;
    if (sv >= bv - MARG) {           // ambiguous: append to compact recheck list
      int slot = atomicAdd(count, 1);
      list[slot] = r0 + tid;
    }
  }
}

// -------- cleanup v5: exact fp32 recompute, 8 rows/unit (unchanged) ---------------
__global__ __launch_bounds__(512) void vq_cleanup(const float* __restrict__ x,
                                                  const float* __restrict__ cb,
                                                  const float* __restrict__ hc,
                                                  const int* __restrict__ list,
                                                  const int* __restrict__ count,
                                                  int* __restrict__ out) {
  __shared__ float xt[8][256];    // 8 KB
  __shared__ int rowids[8];
  __shared__ float wbv[8][8];
  __shared__ int   wbi[8][8];
  const int tid = threadIdx.x;
  const int wave = tid >> 6;
  const int n = *count;

  for (int t0 = blockIdx.x * 8; t0 < n; t0 += gridDim.x * 8) {
    __syncthreads();  // protect LDS reuse across grid-stride iterations
    if (tid < 8) rowids[tid] = (t0 + tid < n) ? list[t0 + tid] : -1;
    __syncthreads();
    {
      int j = tid >> 6, seg = tid & 63;
      int row = rowids[j];
      if (row < 0) row = rowids[0];  // dead slot: stage any valid row (result unused)
      *reinterpret_cast<float4*>(&xt[j][seg * 4]) =
          *reinterpret_cast<const float4*>(x + (size_t)row * 256 + seg * 4);
    }
    __syncthreads();

    float acc0[8], acc1[8];
#pragma unroll
    for (int j = 0; j < 8; ++j) { acc0[j] = 0.f; acc1[j] = 0.f; }

    const float* c0 = cb + (size_t)tid * 256;
    const float* c1 = cb + (size_t)(512 + tid) * 256;
#pragma unroll 4
    for (int d0 = 0; d0 < 256; d0 += 4) {
      float4 ca = *reinterpret_cast<const float4*>(c0 + d0);
      float4 cd = *reinterpret_cast<const float4*>(c1 + d0);
#pragma unroll
      for (int j = 0; j < 8; ++j) {
        float4 xv = *reinterpret_cast<const float4*>(&xt[j][d0]);  // wave-broadcast
        acc0[j] = fmaf(ca.x, xv.x, acc0[j]);
        acc0[j] = fmaf(ca.y, xv.y, acc0[j]);
        acc0[j] = fmaf(ca.z, xv.z, acc0[j]);
        acc0[j] = fmaf(ca.w, xv.w, acc0[j]);
        acc1[j] = fmaf(cd.x, xv.x, acc1[j]);
        acc1[j] = fmaf(cd.y, xv.y, acc1[j]);
        acc1[j] = fmaf(cd.z, xv.z, acc1[j]);
        acc1[j] = fmaf(cd.w, xv.w, acc1[j]);
      }
    }

    const float h0 = hc[tid];
    const float h1 = hc[512 + tid];

#pragma unroll
    for (int j = 0; j < 8; ++j) {
      float bv = acc0[j] - h0; int bi = tid;
      float s1 = acc1[j] - h1;
      if (s1 > bv) { bv = s1; bi = 512 + tid; }  // codes ascending -> strict >
#pragma unroll
      for (int m = 1; m < 64; m <<= 1) {
        float ov = __shfl_xor(bv, m, 64);
        int   oi = __shfl_xor(bi, m, 64);
        bool gt = (ov > bv) || (ov == bv && oi < bi);
        bv = gt ? ov : bv;
        bi = gt ? oi : bi;
      }
      if ((tid & 63) == 0) { wbv[wave][j] = bv; wbi[wave][j] = bi; }
    }
    __syncthreads();
    if (tid < 8 && rowids[tid] >= 0) {
      float bv = wbv[0][tid]; int bi = wbi[0][tid];
#pragma unroll
      for (int w2 = 1; w2 < 8; ++w2) {
        float ov = wbv[w2][tid]; int oi = wbi[w2][tid];
        if (ov > bv || (ov == bv && oi < bi)) { bv = ov; bi = oi; }
      }
      out[rowids[tid]] = bi;
    }
  }
}

// ================= fallback fp32 path (R2 kernel) if ws is too small =================
#define BM 128
#define BN 256
#define BD 32
#define NT 512

__global__ __launch_bounds__(256) void vq_c2_kernel(const float* __restrict__ cb,
                                                    float* __restrict__ halfc2) {
  int row  = blockIdx.x * 4 + (threadIdx.x >> 6);
  int lane = threadIdx.x & 63;
  float4 v = *reinterpret_cast<const float4*>(cb + (size_t)row * 256 + lane * 4);
  float s = v.x * v.x + v.y * v.y + v.z * v.z + v.w * v.w;
#pragma unroll
  for (int m = 32; m >= 1; m >>= 1) s += __shfl_xor(s, m, 64);
  if (lane == 0) halfc2[row] = 0.5f * s;
}

__global__ __launch_bounds__(NT, 2) void vq_argmin_kernel(
    const float* __restrict__ x, const float* __restrict__ cb,
    const float* __restrict__ halfc2, int* __restrict__ out) {
  __shared__ float lds[2][(BM + BN) * BD];
  __shared__ float c2s[1024];
  const int tid = threadIdx.x;
  const int w   = tid >> 6;
  const int tc  = tid & 31;
  const int tr  = tid >> 5;
  const int r0  = blockIdx.x * BM;
  reinterpret_cast<float2*>(c2s)[tid] = reinterpret_cast<const float2*>(halfc2)[tid];
  const int sA  = tr & 7;
  const int sB  = tc & 7;
  const int sAB = sA ^ sB;
  const int cho = (((tid & 7) ^ w)) * 4;
  const int sub = tid >> 3;
  float bestv[8]; int besti[8];
#pragma unroll
  for (int i = 0; i < 8; ++i) { bestv[i] = -3.4e38f; besti[i] = 0; }
  auto stage = [&](int n0, int d0, int p) {
    float* dst  = &lds[p][0];
    float* dstB = dst + BM * BD;
#pragma unroll
    for (int r = 0; r < 2; ++r) {
      int t2 = r * NT + tid;
      glds16(x + (size_t)(r0 + r * 64 + sub) * 256 + d0 + cho, dst + t2 * 4);
    }
#pragma unroll
    for (int r = 0; r < 4; ++r) {
      int t2 = r * NT + tid;
      glds16(cb + (size_t)(n0 + r * 64 + sub) * 256 + d0 + cho, dstB + t2 * 4);
    }
  };
  stage(0, 0, 0);
  int t = 0;
  for (int nt = 0; nt < 4; ++nt) {
    float acc[8][8];
#pragma unroll
    for (int i = 0; i < 8; ++i)
#pragma unroll
      for (int j = 0; j < 8; ++j) acc[i][j] = 0.f;
    for (int dt = 0; dt < 8; ++dt, ++t) {
      const int p = t & 1;
      if (t < 31) {
        const int t1 = t + 1;
        stage((t1 >> 3) * BN, (t1 & 7) * BD, t1 & 1);
        asm volatile("s_waitcnt vmcnt(6)" ::: "memory");
      } else {
        asm volatile("s_waitcnt vmcnt(0)" ::: "memory");
      }
      __builtin_amdgcn_s_barrier();
      const float* pA = &lds[p][tr * 8 * BD];
      const float* pB = &lds[p][BM * BD + tc * 8 * BD];
#pragma unroll
      for (int cc = 0; cc < 8; ++cc) {
        const float* pBc = pB + ((cc ^ sAB) << 2);
        float4 a[8], b[8];
#pragma unroll
        for (int i = 0; i < 8; ++i)
          a[i] = *reinterpret_cast<const float4*>(pA + i * BD + cc * 4);
#pragma unroll
        for (int j = 0; j < 8; ++j)
          b[j] = *reinterpret_cast<const float4*>(pBc + j * BD);
#pragma unroll
        for (int i = 0; i < 8; ++i)
#pragma unroll
          for (int j = 0; j < 8; ++j) {
            acc[i][j] = fmaf(a[i].x, b[j].x, acc[i][j]);
            acc[i][j] = fmaf(a[i].y, b[j].y, acc[i][j]);
            acc[i][j] = fmaf(a[i].z, b[j].z, acc[i][j]);
            acc[i][j] = fmaf(a[i].w, b[j].w, acc[i][j]);
          }
      }
      asm volatile("s_waitcnt lgkmcnt(0)" ::: "memory");
      __builtin_amdgcn_s_barrier();
    }
    const int n0 = nt * BN;
#pragma unroll
    for (int j = 0; j < 8; ++j) {
      const int code = n0 + tc * 8 + j;
      const float hc = c2s[code];
#pragma unroll
      for (int i = 0; i < 8; ++i) {
        float s = acc[i][j] - hc;
        if (s > bestv[i]) { bestv[i] = s; besti[i] = code; }
      }
    }
  }
#pragma unroll
  for (int i = 0; i < 8; ++i) {
#pragma unroll
    for (int m = 1; m <= 16; m <<= 1) {
      float ov = __shfl_xor(bestv[i], m, 64);
      int   oi = __shfl_xor(besti[i], m, 64);
      if (ov > bestv[i] || (ov == bestv[i] && oi < besti[i])) { bestv[i] = ov; besti[i] = oi; }
    }
  }
  if (tc == 0) {
#pragma unroll
    for (int i = 0; i < 8; ++i) out[r0 + tr * 8 + i] = besti[i];
  }
}

// ==================================== launch ====================================
extern "C" void kernel_launch(void* const* d_in, const int* in_sizes, int n_in,
                              void* d_out, int out_size, void* d_ws, size_t ws_size,
                              hipStream_t stream) {
  const float* x  = (const float*)d_in[0];   // (8,4096,256) fp32
  const float* cb = (const float*)d_in[1];   // (1024,256) fp32
  int* out = (int*)d_out;                    // (8,4096) int32

  // ws layout (bytes): cbh 512K | hc 4K | list 128K | count 4
  const size_t OFF_CH = 0;
  const size_t OFF_HC = OFF_CH + (size_t)1024 * 256 * 2;
  const size_t OFF_LS = OFF_HC + (size_t)1024 * 4;
  const size_t OFF_CT = OFF_LS + (size_t)32768 * 4;
  const size_t NEED   = OFF_CT + 64;

  if (ws_size >= NEED) {
    unsigned short* cbh = (unsigned short*)((char*)d_ws + OFF_CH);
    float* hc  = (float*)((char*)d_ws + OFF_HC);
    int* list  = (int*)((char*)d_ws + OFF_LS);
    int* count = (int*)((char*)d_ws + OFF_CT);

    hipLaunchKernelGGL(vq_prep_cb, dim3(256), dim3(256), 0, stream, cb, cbh, hc, count);
    hipLaunchKernelGGL(vq_mfma_kernel, dim3(512), dim3(512), 0, stream,
                       x, cbh, hc, out, list, count);
    hipLaunchKernelGGL(vq_cleanup, dim3(512), dim3(512), 0, stream,
                       x, cb, hc, list, count, out);
  } else {
    float* c2 = (float*)d_ws;
    hipLaunchKernelGGL(vq_c2_kernel, dim3(256), dim3(256), 0, stream, cb, c2);
    hipLaunchKernelGGL(vq_argmin_kernel, dim3(32768 / BM), dim3(NT), 0, stream,
                       x, cb, c2, out);
  }
}

// Round 16
// 68.495 us; speedup vs baseline: 1.4425x; 1.4425x over previous
//
#include <hip/hip_runtime.h>
#include <stdint.h>

typedef __attribute__((ext_vector_type(8))) _Float16 f16x8;
typedef __attribute__((ext_vector_type(4))) float f32x4;

#define MARG 0.09375f

// async global->LDS, 16B per lane (used by fallback path)
__device__ __forceinline__ void glds16(const void* g, void* l) {
  __builtin_amdgcn_global_load_lds(
      (const __attribute__((address_space(1))) void*)g,
      (__attribute__((address_space(3))) void*)l, 16, 0, 0);
}

__device__ __forceinline__ unsigned short f2h(float f) {
  return __builtin_bit_cast(unsigned short, (_Float16)f);  // RN
}

// ---- prep cb v2: fp16 convert + hc + TRANSPOSED fp32 copy cbT[256][1024] ----
// 64 blocks x 256 thr; block handles 16 codebook rows via a padded LDS tile.
__global__ __launch_bounds__(256) void vq_prep_cb(const float* __restrict__ cb,
                                                  unsigned short* __restrict__ cbh,
                                                  float* __restrict__ hc,
                                                  float* __restrict__ cbT,
                                                  int* __restrict__ count) {
  __shared__ float tile[16][260];  // +4 pad: column reads spread banks
  const int tid = threadIdx.x;
  const int r0 = blockIdx.x * 16;
  const int lane = tid & 63;
  const int wave = tid >> 6;

  // load 16 rows (4 rounds of 4 rows), write cbh on the way
#pragma unroll
  for (int i = 0; i < 4; ++i) {
    int r = i * 4 + (tid >> 6);
    int d = lane * 4;
    float4 v = *reinterpret_cast<const float4*>(cb + (size_t)(r0 + r) * 256 + d);
    *reinterpret_cast<float4*>(&tile[r][d]) = v;
    ushort4 h;
    h.x = f2h(v.x); h.y = f2h(v.y); h.z = f2h(v.z); h.w = f2h(v.w);
    *reinterpret_cast<ushort4*>(cbh + (size_t)(r0 + r) * 256 + d) = h;
  }
  __syncthreads();

  // hc: wave w reduces rows w*4..w*4+3
#pragma unroll
  for (int i = 0; i < 4; ++i) {
    int r = wave * 4 + i;
    float4 v = *reinterpret_cast<const float4*>(&tile[r][lane * 4]);
    float s = v.x * v.x + v.y * v.y + v.z * v.z + v.w * v.w;
#pragma unroll
    for (int m = 32; m >= 1; m >>= 1) s += __shfl_xor(s, m, 64);
    if (lane == 0) hc[r0 + r] = 0.5f * s;
  }

  // cbT: thread t owns dim d=t; writes one full 64B line (16 codes) as 4 float4
  {
    const int d = tid;
#pragma unroll
    for (int i = 0; i < 4; ++i) {
      float4 v = make_float4(tile[i * 4 + 0][d], tile[i * 4 + 1][d],
                             tile[i * 4 + 2][d], tile[i * 4 + 3][d]);
      *reinterpret_cast<float4*>(cbT + (size_t)d * 1024 + r0 + i * 4) = v;
    }
  }
  if (blockIdx.x == 0 && tid == 0) *count = 0;
}

// ------- main (R10 kernel, best profiled): fused x-convert fp16 MFMA, BM=64 -------
// 512 thr = 8 waves (2M x 4N), wave tile 32 rows x 64 cols, block 64 rows x 1024
// codes (4 chunks of 256). Phase 0: load block's A rows fp32 -> cvt fp16 -> A_lds
// (32KB, single-buffered, XOR-swizzled byte^=(row&7)<<4 on BOTH write and read).
// K-loop stages only B (double-buffered 2x16KB, vmcnt(2)). ~71KB LDS -> 2 blk/CU.
__global__ __launch_bounds__(512, 4) void vq_mfma_kernel(
    const float* __restrict__ x, const unsigned short* __restrict__ cbh,
    const float* __restrict__ hc, int* __restrict__ out,
    int* __restrict__ list, int* __restrict__ count) {
  __shared__ unsigned short Alds[16384];  // 32 KB: 64 rows x 256 fp16 (swizzled)
  __shared__ unsigned short Blds[16384];  // 32 KB: 2 x (256 codes x 32 dims)
  __shared__ float c2s[1024];             // 4 KB
  __shared__ float cbv[4][64];            // cross-wave merge: best
  __shared__ int   cbi[4][64];            //   index
  __shared__ float csv[4][64];            //   second-best

  const int tid = threadIdx.x;
  const int lane = tid & 63;
  const int wave = tid >> 6;
  const int wr = wave >> 2;   // 0..1 (M)
  const int wc = wave & 3;    // 0..3 (N)
  const int l15 = lane & 15;
  const int l4  = lane >> 4;  // 0..3
  // XCD-aware swizzle: 512 blocks, 8 XCDs -> contiguous 64-block chunks per XCD
  const int bswz = (blockIdx.x & 7) * 64 + (blockIdx.x >> 3);
  const int r0 = bswz * 64;

  reinterpret_cast<float2*>(c2s)[tid] = reinterpret_cast<const float2*>(hc)[tid];

  // ---- Phase 0: A rows fp32 -> fp16 -> A_lds (once per block) ----
  {
    const int row = tid >> 3;          // 0..63
    const int cc  = tid & 7;           // col chunk (32 dims)
    const float* src = x + (size_t)(r0 + row) * 256 + cc * 32;
    unsigned short hv[32];
#pragma unroll
    for (int q = 0; q < 8; ++q) {
      float4 v = *reinterpret_cast<const float4*>(src + q * 4);
      hv[q * 4 + 0] = f2h(v.x); hv[q * 4 + 1] = f2h(v.y);
      hv[q * 4 + 2] = f2h(v.z); hv[q * 4 + 3] = f2h(v.w);
    }
    char* base = reinterpret_cast<char*>(Alds);
#pragma unroll
    for (int g = 0; g < 4; ++g) {
      int byte = (row * 512 + cc * 64 + g * 16) ^ ((row & 7) << 4);
      *reinterpret_cast<f16x8*>(base + byte) = *reinterpret_cast<const f16x8*>(&hv[g * 8]);
    }
  }

  // B staging: dest linear 16B granules; source chunk pre-swizzled by (code>>1)&3.
  auto stage = [&](int T1) {
    const int p = T1 & 1;
    const int n0 = (T1 >> 3) << 8;
    const int d0 = (T1 & 7) << 5;
    unsigned short* B = Blds + p * 8192;
#pragma unroll
    for (int r = 0; r < 2; ++r) {
      int idx = r * 512 + tid;
      int bch = (idx & 3) ^ ((idx >> 3) & 3);
      glds16(cbh + (size_t)(n0 + (idx >> 2)) * 256 + d0 + bch * 8, B + idx * 8);
    }
  };

  float bestv[2][4], secondv[2][4];
  int besti[2][4];
#pragma unroll
  for (int tr = 0; tr < 2; ++tr)
#pragma unroll
    for (int g = 0; g < 4; ++g) {
      bestv[tr][g] = -3.4e38f; secondv[tr][g] = -3.4e38f; besti[tr][g] = 0;
    }

  __syncthreads();   // A_lds complete
  stage(0);          // prologue: 2 glds in flight

  const int swzf = (l15 >> 1) & 3;  // B read-side chunk XOR ((code>>1)&3)
  // A fragment base byte addresses (per tr), swizzle folded in; dt/l4 offsets added in-loop
  int abase[2];
#pragma unroll
  for (int tr = 0; tr < 2; ++tr) {
    int arow = wr * 32 + tr * 16 + l15;
    abase[tr] = (arow * 512 + l4 * 16) ^ ((arow & 7) << 4);
  }

  int T = 0;
  for (int nt = 0; nt < 4; ++nt) {
    f32x4 acc[2][4];
#pragma unroll
    for (int tr = 0; tr < 2; ++tr)
#pragma unroll
      for (int tc = 0; tc < 4; ++tc) acc[tr][tc] = (f32x4){0.f, 0.f, 0.f, 0.f};

    for (int dt = 0; dt < 8; ++dt, ++T) {
      const int p = T & 1;
      if (T < 31) {
        stage(T + 1);
        // 2 newest (next stage) stay in flight; stage T's 2 are complete.
        asm volatile("s_waitcnt vmcnt(2)" ::: "memory");
      } else {
        asm volatile("s_waitcnt vmcnt(0)" ::: "memory");
      }
      __builtin_amdgcn_s_barrier();

      const char* Ab = reinterpret_cast<const char*>(Alds);
      const unsigned short* B = Blds + p * 8192;

      f16x8 af[2], bf[4];
#pragma unroll
      for (int tr = 0; tr < 2; ++tr)
        af[tr] = *reinterpret_cast<const f16x8*>(Ab + (abase[tr] ^ (dt * 64)));
#pragma unroll
      for (int tc = 0; tc < 4; ++tc) {
        int bcol = wc * 64 + tc * 16 + l15;
        bf[tc] = *reinterpret_cast<const f16x8*>(B + bcol * 32 + (l4 ^ swzf) * 8);
      }

#pragma unroll
      for (int tr = 0; tr < 2; ++tr)
#pragma unroll
        for (int tc = 0; tc < 4; ++tc)
          acc[tr][tc] = __builtin_amdgcn_mfma_f32_16x16x32_f16(af[tr], bf[tc], acc[tr][tc], 0, 0, 0);

      asm volatile("s_waitcnt lgkmcnt(0)" ::: "memory");
      __builtin_amdgcn_s_barrier();
    }

    // fold chunk scores into running best/second (codes ascending per thread)
    const int cb0 = nt * 256 + wc * 64 + l15;
    float hcv[4];
#pragma unroll
    for (int tc = 0; tc < 4; ++tc) hcv[tc] = c2s[cb0 + tc * 16];
#pragma unroll
    for (int tr = 0; tr < 2; ++tr)
#pragma unroll
      for (int tc = 0; tc < 4; ++tc) {
        const int code = cb0 + tc * 16;
#pragma unroll
        for (int g = 0; g < 4; ++g) {
          float s = acc[tr][tc][g] - hcv[tc];
          bool gt = s > bestv[tr][g];
          float ns = gt ? bestv[tr][g] : fmaxf(secondv[tr][g], s);
          bestv[tr][g] = gt ? s : bestv[tr][g];
          besti[tr][g] = gt ? code : besti[tr][g];
          secondv[tr][g] = ns;
        }
      }
  }

  // within-wave merge across the 16 l15-lanes sharing each row-slot
#pragma unroll
  for (int tr = 0; tr < 2; ++tr)
#pragma unroll
    for (int g = 0; g < 4; ++g) {
      float bv = bestv[tr][g]; int bi = besti[tr][g]; float sv = secondv[tr][g];
#pragma unroll
      for (int m = 1; m < 16; m <<= 1) {
        float ov = __shfl_xor(bv, m, 64);
        int   oi = __shfl_xor(bi, m, 64);
        float os = __shfl_xor(sv, m, 64);
        sv = fmaxf(fmaxf(sv, os), fminf(bv, ov));
        bool gt = (ov > bv) || (ov == bv && oi < bi);
        bv = gt ? ov : bv;
        bi = gt ? oi : bi;
      }
      if (l15 == 0) {
        int rl = wr * 32 + tr * 16 + l4 * 4 + g;
        cbv[wc][rl] = bv; cbi[wc][rl] = bi; csv[wc][rl] = sv;
      }
    }

  // cross-wave merge: each of 4 wc-waves surveyed a disjoint 64-code slice per chunk
  __syncthreads();
  if (tid < 64) {
    float bv = cbv[0][tid]; int bi = cbi[0][tid]; float sv = csv[0][tid];
#pragma unroll
    for (int w2 = 1; w2 < 4; ++w2) {
      float ov = cbv[w2][tid]; int oi = cbi[w2][tid]; float os = csv[w2][tid];
      sv = fmaxf(fmaxf(sv, os), fminf(bv, ov));
      bool gt = (ov > bv) || (ov == bv && oi < bi);
      bv = gt ? ov : bv;
      bi = gt ? oi : bi;
    }
    out[r0 + tid] = bi;
    if (sv >= bv - MARG) {           // ambiguous: append to compact recheck list
      int slot = atomicAdd(count, 1);
      list[slot] = r0 + tid;
    }
  }
}

// -------- cleanup v6: exact fp32 recompute from TRANSPOSED codebook --------
// 4 rows/unit, 1024-block grid. Thread owns 4 CONSECUTIVE codes -> cbT[d][c0..c0+3]
// loads are perfectly coalesced (16B/lane); x broadcast from LDS; 2048 FMA/thread.
// Half-block (4 waves) handles 2 rows each.
__global__ __launch_bounds__(512) void vq_cleanup(const float* __restrict__ x,
                                                  const float* __restrict__ cbT,
                                                  const float* __restrict__ hc,
                                                  const int* __restrict__ list,
                                                  const int* __restrict__ count,
                                                  int* __restrict__ out) {
  __shared__ float xt[4][256];    // 4 KB
  __shared__ int rowids[4];
  __shared__ float wbv[8][2];     // per wave x per local row
  __shared__ int   wbi[8][2];
  const int tid = threadIdx.x;
  const int wave = tid >> 6;
  const int half = tid >> 8;          // 0: rows 0-1, 1: rows 2-3
  const int c0 = (tid & 255) * 4;     // 4 consecutive codes
  const int n = *count;

  for (int t0 = blockIdx.x * 4; t0 < n; t0 += gridDim.x * 4) {
    __syncthreads();  // protect LDS reuse across grid-stride iterations
    if (tid < 4) rowids[tid] = (t0 + tid < n) ? list[t0 + tid] : -1;
    __syncthreads();
    {
      int j = tid >> 7, seg = tid & 127;
      int row = rowids[j];
      if (row < 0) row = rowids[0];  // dead slot: stage any valid row (result unused)
      *reinterpret_cast<float2*>(&xt[j][seg * 2]) =
          *reinterpret_cast<const float2*>(x + (size_t)row * 256 + seg * 2);
    }
    __syncthreads();

    float a0[4], a1[4];
#pragma unroll
    for (int k = 0; k < 4; ++k) { a0[k] = 0.f; a1[k] = 0.f; }

    const float4* cvp = reinterpret_cast<const float4*>(cbT) + (c0 >> 2);
    const float* xr0 = &xt[half * 2 + 0][0];
    const float* xr1 = &xt[half * 2 + 1][0];
#pragma unroll 4
    for (int d = 0; d < 256; ++d) {
      float4 cv = cvp[d * 256];         // cbT[d][c0..c0+3], coalesced
      float x0 = xr0[d];                // LDS broadcast
      float x1 = xr1[d];
      a0[0] = fmaf(cv.x, x0, a0[0]); a0[1] = fmaf(cv.y, x0, a0[1]);
      a0[2] = fmaf(cv.z, x0, a0[2]); a0[3] = fmaf(cv.w, x0, a0[3]);
      a1[0] = fmaf(cv.x, x1, a1[0]); a1[1] = fmaf(cv.y, x1, a1[1]);
      a1[2] = fmaf(cv.z, x1, a1[2]); a1[3] = fmaf(cv.w, x1, a1[3]);
    }

    float4 hcv = *reinterpret_cast<const float4*>(hc + c0);

#pragma unroll
    for (int r = 0; r < 2; ++r) {
      const float* a = (r == 0) ? a0 : a1;
      // local best among 4 ascending codes (strict > keeps first)
      float bv = a[0] - hcv.x; int bi = c0;
      float s1 = a[1] - hcv.y; if (s1 > bv) { bv = s1; bi = c0 + 1; }
      float s2 = a[2] - hcv.z; if (s2 > bv) { bv = s2; bi = c0 + 2; }
      float s3 = a[3] - hcv.w; if (s3 > bv) { bv = s3; bi = c0 + 3; }
#pragma unroll
      for (int m = 1; m < 64; m <<= 1) {
        float ov = __shfl_xor(bv, m, 64);
        int   oi = __shfl_xor(bi, m, 64);
        bool gt = (ov > bv) || (ov == bv && oi < bi);
        bv = gt ? ov : bv;
        bi = gt ? oi : bi;
      }
      if ((tid & 63) == 0) { wbv[wave][r] = bv; wbi[wave][r] = bi; }
    }
    __syncthreads();
    if (tid < 4 && rowids[tid] >= 0) {
      int h2 = tid >> 1, lr = tid & 1;           // row tid -> half h2, local row lr
      int wbase = h2 * 4;
      float bv = wbv[wbase][lr]; int bi = wbi[wbase][lr];
#pragma unroll
      for (int w2 = 1; w2 < 4; ++w2) {
        float ov = wbv[wbase + w2][lr]; int oi = wbi[wbase + w2][lr];
        if (ov > bv || (ov == bv && oi < bi)) { bv = ov; bi = oi; }
      }
      out[rowids[tid]] = bi;
    }
  }
}

// ================= fallback fp32 path (R2 kernel) if ws is too small =================
#define BM 128
#define BN 256
#define BD 32
#define NT 512

__global__ __launch_bounds__(256) void vq_c2_kernel(const float* __restrict__ cb,
                                                    float* __restrict__ halfc2) {
  int row  = blockIdx.x * 4 + (threadIdx.x >> 6);
  int lane = threadIdx.x & 63;
  float4 v = *reinterpret_cast<const float4*>(cb + (size_t)row * 256 + lane * 4);
  float s = v.x * v.x + v.y * v.y + v.z * v.z + v.w * v.w;
#pragma unroll
  for (int m = 32; m >= 1; m >>= 1) s += __shfl_xor(s, m, 64);
  if (lane == 0) halfc2[row] = 0.5f * s;
}

__global__ __launch_bounds__(NT, 2) void vq_argmin_kernel(
    const float* __restrict__ x, const float* __restrict__ cb,
    const float* __restrict__ halfc2, int* __restrict__ out) {
  __shared__ float lds[2][(BM + BN) * BD];
  __shared__ float c2s[1024];
  const int tid = threadIdx.x;
  const int w   = tid >> 6;
  const int tc  = tid & 31;
  const int tr  = tid >> 5;
  const int r0  = blockIdx.x * BM;
  reinterpret_cast<float2*>(c2s)[tid] = reinterpret_cast<const float2*>(halfc2)[tid];
  const int sA  = tr & 7;
  const int sB  = tc & 7;
  const int sAB = sA ^ sB;
  const int cho = (((tid & 7) ^ w)) * 4;
  const int sub = tid >> 3;
  float bestv[8]; int besti[8];
#pragma unroll
  for (int i = 0; i < 8; ++i) { bestv[i] = -3.4e38f; besti[i] = 0; }
  auto stage = [&](int n0, int d0, int p) {
    float* dst  = &lds[p][0];
    float* dstB = dst + BM * BD;
#pragma unroll
    for (int r = 0; r < 2; ++r) {
      int t2 = r * NT + tid;
      glds16(x + (size_t)(r0 + r * 64 + sub) * 256 + d0 + cho, dst + t2 * 4);
    }
#pragma unroll
    for (int r = 0; r < 4; ++r) {
      int t2 = r * NT + tid;
      glds16(cb + (size_t)(n0 + r * 64 + sub) * 256 + d0 + cho, dstB + t2 * 4);
    }
  };
  stage(0, 0, 0);
  int t = 0;
  for (int nt = 0; nt < 4; ++nt) {
    float acc[8][8];
#pragma unroll
    for (int i = 0; i < 8; ++i)
#pragma unroll
      for (int j = 0; j < 8; ++j) acc[i][j] = 0.f;
    for (int dt = 0; dt < 8; ++dt, ++t) {
      const int p = t & 1;
      if (t < 31) {
        const int t1 = t + 1;
        stage((t1 >> 3) * BN, (t1 & 7) * BD, t1 & 1);
        asm volatile("s_waitcnt vmcnt(6)" ::: "memory");
      } else {
        asm volatile("s_waitcnt vmcnt(0)" ::: "memory");
      }
      __builtin_amdgcn_s_barrier();
      const float* pA = &lds[p][tr * 8 * BD];
      const float* pB = &lds[p][BM * BD + tc * 8 * BD];
#pragma unroll
      for (int cc = 0; cc < 8; ++cc) {
        const float* pBc = pB + ((cc ^ sAB) << 2);
        float4 a[8], b[8];
#pragma unroll
        for (int i = 0; i < 8; ++i)
          a[i] = *reinterpret_cast<const float4*>(pA + i * BD + cc * 4);
#pragma unroll
        for (int j = 0; j < 8; ++j)
          b[j] = *reinterpret_cast<const float4*>(pBc + j * BD);
#pragma unroll
        for (int i = 0; i < 8; ++i)
#pragma unroll
          for (int j = 0; j < 8; ++j) {
            acc[i][j] = fmaf(a[i].x, b[j].x, acc[i][j]);
            acc[i][j] = fmaf(a[i].y, b[j].y, acc[i][j]);
            acc[i][j] = fmaf(a[i].z, b[j].z, acc[i][j]);
            acc[i][j] = fmaf(a[i].w, b[j].w, acc[i][j]);
          }
      }
      asm volatile("s_waitcnt lgkmcnt(0)" ::: "memory");
      __builtin_amdgcn_s_barrier();
    }
    const int n0 = nt * BN;
#pragma unroll
    for (int j = 0; j < 8; ++j) {
      const int code = n0 + tc * 8 + j;
      const float hc = c2s[code];
#pragma unroll
      for (int i = 0; i < 8; ++i) {
        float s = acc[i][j] - hc;
        if (s > bestv[i]) { bestv[i] = s; besti[i] = code; }
      }
    }
  }
#pragma unroll
  for (int i = 0; i < 8; ++i) {
#pragma unroll
    for (int m = 1; m <= 16; m <<= 1) {
      float ov = __shfl_xor(bestv[i], m, 64);
      int   oi = __shfl_xor(besti[i], m, 64);
      if (ov > bestv[i] || (ov == bestv[i] && oi < besti[i])) { bestv[i] = ov; besti[i] = oi; }
    }
  }
  if (tc == 0) {
#pragma unroll
    for (int i = 0; i < 8; ++i) out[r0 + tr * 8 + i] = besti[i];
  }
}

// ==================================== launch ====================================
extern "C" void kernel_launch(void* const* d_in, const int* in_sizes, int n_in,
                              void* d_out, int out_size, void* d_ws, size_t ws_size,
                              hipStream_t stream) {
  const float* x  = (const float*)d_in[0];   // (8,4096,256) fp32
  const float* cb = (const float*)d_in[1];   // (1024,256) fp32
  int* out = (int*)d_out;                    // (8,4096) int32

  // ws layout (bytes): cbh 512K | hc 4K | cbT 1M | list 128K | count 4
  const size_t OFF_CH  = 0;
  const size_t OFF_HC  = OFF_CH + (size_t)1024 * 256 * 2;
  const size_t OFF_CBT = OFF_HC + (size_t)1024 * 4;
  const size_t OFF_LS  = OFF_CBT + (size_t)1024 * 256 * 4;
  const size_t OFF_CT  = OFF_LS + (size_t)32768 * 4;
  const size_t NEED    = OFF_CT + 64;

  if (ws_size >= NEED) {
    unsigned short* cbh = (unsigned short*)((char*)d_ws + OFF_CH);
    float* hc  = (float*)((char*)d_ws + OFF_HC);
    float* cbT = (float*)((char*)d_ws + OFF_CBT);
    int* list  = (int*)((char*)d_ws + OFF_LS);
    int* count = (int*)((char*)d_ws + OFF_CT);

    hipLaunchKernelGGL(vq_prep_cb, dim3(64), dim3(256), 0, stream, cb, cbh, hc, cbT, count);
    hipLaunchKernelGGL(vq_mfma_kernel, dim3(512), dim3(512), 0, stream,
                       x, cbh, hc, out, list, count);
    hipLaunchKernelGGL(vq_cleanup, dim3(1024), dim3(512), 0, stream,
                       x, cbT, hc, list, count, out);
  } else {
    float* c2 = (float*)d_ws;
    hipLaunchKernelGGL(vq_c2_kernel, dim3(256), dim3(256), 0, stream, cb, c2);
    hipLaunchKernelGGL(vq_argmin_kernel, dim3(32768 / BM), dim3(NT), 0, stream,
                       x, cb, c2, out);
  }
}